// Round 5
// baseline (325.126 us; speedup 1.0000x reference)
//
#include <hip/hip_runtime.h>

// B=8, C=256, H=W=48 -> N=2304, k=4 -> CK=64
#define BATCH 8
#define CIN   256
#define NPIX  2304
#define CKD   64
#define QKLD  128          // qkT row stride (q cols 0-63, k cols 64-127)

typedef _Float16 f16;
typedef __attribute__((ext_vector_type(4))) _Float16 f16x4;
typedef __attribute__((ext_vector_type(8))) _Float16 f16x8;
typedef __attribute__((ext_vector_type(4))) float    f32x4;

// ---------------------------------------------------------------------------
// Cast all conv weights fp32 -> f16. Wqk = [qw (64x256); kw (64x256)].
// ---------------------------------------------------------------------------
__global__ __launch_bounds__(256) void cast_w(
    const float* __restrict__ qw, const float* __restrict__ kw,
    const float* __restrict__ vw, const float* __restrict__ gw,
    f16* __restrict__ Wqk, f16* __restrict__ Wv, f16* __restrict__ Wg)
{
    int idx = (blockIdx.x * 256 + threadIdx.x) * 4;
    const float* src;
    f16* dst;
    if (idx < 16384)      { src = qw + idx;           dst = Wqk + idx; }
    else if (idx < 32768) { src = kw + (idx - 16384); dst = Wqk + idx; }
    else if (idx < 98304) { src = vw + (idx - 32768); dst = Wv + (idx - 32768); }
    else                  { src = gw + (idx - 98304); dst = Wg + (idx - 98304); }
    float4 v = *(const float4*)src;
    f16x4 h = { (f16)v.x, (f16)v.y, (f16)v.z, (f16)v.w };
    *(f16x4*)dst = h;
}

// ---------------------------------------------------------------------------
// x[b][c][n] fp32 -> xT[b][n][c] f16 (LDS transpose). Tile 64c x 64n.
// ---------------------------------------------------------------------------
__global__ __launch_bounds__(256) void cast_xT(
    const float* __restrict__ x, f16* __restrict__ xT)
{
    __shared__ float s[64][65];
    const int t = threadIdx.x;
    const int n0 = blockIdx.x * 64, c0 = blockIdx.y * 64, b = blockIdx.z;
    const float* xb = x + ((size_t)b * CIN + c0) * NPIX + n0;

    const int cl = t >> 4, ng = (t & 15) * 4;
    #pragma unroll
    for (int p = 0; p < 4; ++p) {
        float4 v = *(const float4*)(xb + (size_t)(cl + 16 * p) * NPIX + ng);
        s[cl + 16 * p][ng + 0] = v.x;
        s[cl + 16 * p][ng + 1] = v.y;
        s[cl + 16 * p][ng + 2] = v.z;
        s[cl + 16 * p][ng + 3] = v.w;
    }
    __syncthreads();
    const int nl = t >> 2, cs = (t & 3) * 16;
    f16 h[16];
    #pragma unroll
    for (int j = 0; j < 16; ++j) h[j] = (f16)s[cs + j][nl];
    f16* gp = &xT[((size_t)b * NPIX + n0 + nl) * CIN + c0 + cs];
    *(f16x8*)gp       = *(f16x8*)&h[0];
    *(f16x8*)(gp + 8) = *(f16x8*)&h[8];
}

// ---------------------------------------------------------------------------
// q & k conv via MFMA: qkT[b][n][o], o<64 = q, o>=64 = k.
// grid (N/32, B), block 256.
// ---------------------------------------------------------------------------
__global__ __launch_bounds__(256) void qk_conv_mfma(
    const f16* __restrict__ xT, const f16* __restrict__ Wqk,
    const float* __restrict__ qbias, const float* __restrict__ kbias,
    f16* __restrict__ qkT)
{
    const int t = threadIdx.x, w = t >> 6, lane = t & 63;
    const int quad = lane >> 4, l16 = lane & 15;
    const int wm = w & 1, wn = w >> 1;
    const int n0 = blockIdx.x * 32, b = blockIdx.y;

    const f16* bp = xT + ((size_t)b * NPIX + n0 + 16 * wn + l16) * CIN;
    const f16* ap = Wqk + (size_t)(64 * wm + l16) * CIN;

    f32x4 acc[4];
    #pragma unroll
    for (int mt = 0; mt < 4; ++mt) acc[mt] = (f32x4){0.f, 0.f, 0.f, 0.f};

    #pragma unroll
    for (int kk = 0; kk < CIN; kk += 32) {
        f16x8 bf = *(const f16x8*)(bp + kk + quad * 8);
        #pragma unroll
        for (int mt = 0; mt < 4; ++mt) {
            f16x8 af = *(const f16x8*)(ap + (size_t)mt * 16 * CIN + kk + quad * 8);
            acc[mt] = __builtin_amdgcn_mfma_f32_16x16x32_f16(af, bf, acc[mt], 0, 0, 0);
        }
    }
    const int n = n0 + 16 * wn + l16;
    const float* bias = wm ? kbias - 64 : qbias;   // o-indexed
    #pragma unroll
    for (int mt = 0; mt < 4; ++mt) {
        int ob = 64 * wm + 16 * mt + quad * 4;
        f16x4 h;
        #pragma unroll
        for (int r = 0; r < 4; ++r)
            h[r] = (f16)(acc[mt][r] + bias[ob + r]);
        *(f16x4*)&qkT[((size_t)b * NPIX + n) * QKLD + ob] = h;
    }
}

// ---------------------------------------------------------------------------
// S-only energy pass: S[b,i] += sum_j f16(exp(q_i . k_j)). No E store.
// grid (N/64 j, N/64 i, B), block 256. S pre-zeroed.
// ---------------------------------------------------------------------------
__global__ __launch_bounds__(256) void energy_S(
    const f16* __restrict__ qkT, float* __restrict__ S)
{
    __shared__ f16   es[64][72];
    __shared__ float red2[4][64];
    const int t    = threadIdx.x;
    const int w    = t >> 6, lane = t & 63;
    const int quad = lane >> 4, l16 = lane & 15;
    const int j0 = blockIdx.x * 64, i0 = blockIdx.y * 64, b = blockIdx.z;
    const f16* base = qkT + (size_t)b * NPIX * QKLD;

    f32x4 acc[4];
    #pragma unroll
    for (int mt = 0; mt < 4; ++mt) acc[mt] = (f32x4){0.f, 0.f, 0.f, 0.f};

    #pragma unroll
    for (int ks = 0; ks < 2; ++ks) {
        f16x8 bf = *(const f16x8*)&base[(size_t)(j0 + 16 * w + l16) * QKLD + 64 + ks * 32 + quad * 8];
        #pragma unroll
        for (int mt = 0; mt < 4; ++mt) {
            f16x8 af = *(const f16x8*)&base[(size_t)(i0 + 16 * mt + l16) * QKLD + ks * 32 + quad * 8];
            acc[mt] = __builtin_amdgcn_mfma_f32_16x16x32_f16(af, bf, acc[mt], 0, 0, 0);
        }
    }

    // f16-rounded tile (matches what fused_bmm will consume)
    #pragma unroll
    for (int mt = 0; mt < 4; ++mt) {
        f16x4 h = { (f16)__expf(acc[mt][0]), (f16)__expf(acc[mt][1]),
                    (f16)__expf(acc[mt][2]), (f16)__expf(acc[mt][3]) };
        *(f16x4*)&es[16 * w + l16][16 * mt + quad * 4] = h;
    }
    __syncthreads();
    {
        int i = t & 63, jq = t >> 6;
        float s = 0.f;
        #pragma unroll
        for (int jj = 0; jj < 16; ++jj)
            s += (float)es[jq * 16 + jj][i];
        red2[jq][i] = s;
    }
    __syncthreads();
    if (t < 64) {
        float s = red2[0][t] + red2[1][t] + red2[2][t] + red2[3][t];
        atomicAdd(&S[(size_t)b * NPIX + i0 + t], s);
    }
}

// ---------------------------------------------------------------------------
// v conv via MFMA, fused bias + 1/S scale: u[b,c,i] f16.
// Tile 128(c) x 64(i), BK=32, LDS-staged. grid (N/64, C/128, B), block 256.
// ---------------------------------------------------------------------------
__global__ __launch_bounds__(256) void v_conv_mfma(
    const f16* __restrict__ xT, const f16* __restrict__ Wv,
    const float* __restrict__ vbias, const float* __restrict__ S,
    f16* __restrict__ u)
{
    __shared__ __align__(16) f16 As[128 * 40];
    __shared__ __align__(16) f16 Bs[64 * 40];
    const int t = threadIdx.x, w = t >> 6, lane = t & 63;
    const int quad = lane >> 4, l16 = lane & 15;
    const int wm = w & 1, wn = w >> 1;
    const int i0 = blockIdx.x * 64, c0 = blockIdx.y * 128, b = blockIdx.z;
    const int sub = t >> 2, le = t & 3;
    const f16* srcA = Wv + (size_t)(c0 + sub) * CIN + le * 8;
    const f16* srcB = xT + ((size_t)b * NPIX + i0 + sub) * CIN + le * 8;
    const int ldsw = sub * 40 + le * 8;

    f32x4 acc[4][2];
    #pragma unroll
    for (int mt = 0; mt < 4; ++mt)
        #pragma unroll
        for (int nt = 0; nt < 2; ++nt)
            acc[mt][nt] = (f32x4){0.f, 0.f, 0.f, 0.f};

    for (int kk = 0; kk < CIN; kk += 32) {
        f16x8 ta0 = *(const f16x8*)(srcA + kk);
        f16x8 ta1 = *(const f16x8*)(srcA + (size_t)64 * CIN + kk);
        f16x8 tb0 = *(const f16x8*)(srcB + kk);
        __syncthreads();
        *(f16x8*)&As[ldsw]           = ta0;
        *(f16x8*)&As[64 * 40 + ldsw] = ta1;
        *(f16x8*)&Bs[ldsw]           = tb0;
        __syncthreads();
        f16x8 af[4], bf[2];
        #pragma unroll
        for (int mt = 0; mt < 4; ++mt)
            af[mt] = *(const f16x8*)&As[(64 * wm + 16 * mt + l16) * 40 + quad * 8];
        #pragma unroll
        for (int nt = 0; nt < 2; ++nt)
            bf[nt] = *(const f16x8*)&Bs[(32 * wn + 16 * nt + l16) * 40 + quad * 8];
        #pragma unroll
        for (int mt = 0; mt < 4; ++mt)
            #pragma unroll
            for (int nt = 0; nt < 2; ++nt)
                acc[mt][nt] = __builtin_amdgcn_mfma_f32_16x16x32_f16(
                    af[mt], bf[nt], acc[mt][nt], 0, 0, 0);
    }

    #pragma unroll
    for (int nt = 0; nt < 2; ++nt) {
        int i = i0 + 32 * wn + 16 * nt + l16;
        float is = 1.0f / S[(size_t)b * NPIX + i];
        #pragma unroll
        for (int mt = 0; mt < 4; ++mt)
            #pragma unroll
            for (int r = 0; r < 4; ++r) {
                int c = c0 + 64 * wm + 16 * mt + quad * 4 + r;
                u[((size_t)b * CIN + c) * NPIX + i] =
                    (f16)((acc[mt][nt][r] + vbias[c]) * is);
            }
    }
}

// ---------------------------------------------------------------------------
// FUSED attention bmm: o1T[b,j,c] = sum_i u[c,i] * exp(q_i . k_j)
// Per block: 64 j x 128 c. Loop i-chunks of 32:
//   stage1: E-tile 32i x 64j via MFMA (A=q rows i, B=k rows j, K=64),
//           exp -> es[j][i] LDS (stride 36 f16; b64 ops, conflict-free)
//   stage2: acc += u-frags (direct global, L2-hot) x es B-frags (K=32)
// grid (N/64, C/128, B), block 256 (4 waves: stage1 j-strip w, stage2 c-sub 32w)
// ---------------------------------------------------------------------------
__global__ __launch_bounds__(256) void fused_bmm(
    const f16* __restrict__ qkT, const f16* __restrict__ u,
    f16* __restrict__ o1T)
{
    __shared__ __align__(16) f16 es[64 * 36];
    const int t = threadIdx.x, w = t >> 6, lane = t & 63;
    const int quad = lane >> 4, l16 = lane & 15;
    const int j0 = blockIdx.x * 64, c0 = blockIdx.y * 128, b = blockIdx.z;

    const f16* qkb = qkT + (size_t)b * NPIX * QKLD;
    // stage1 B-frags (k rows, loop-invariant): row j = j0 + 16w + l16
    const f16* kp = qkb + (size_t)(j0 + 16 * w + l16) * QKLD + 64;
    f16x8 kf0 = *(const f16x8*)(kp + quad * 8);
    f16x8 kf1 = *(const f16x8*)(kp + 32 + quad * 8);
    // stage1 A rows: i = i0 + {0,16} + l16 (all waves identical -> L1 broadcast)
    const f16* qp = qkb + (size_t)l16 * QKLD + quad * 8;
    // stage2 A rows: c = c0 + 32w + 16mt + l16
    const f16* up0 = u + ((size_t)b * CIN + c0 + 32 * w + l16) * NPIX;
    const f16* up1 = up0 + (size_t)16 * NPIX;

    f32x4 acc[2][4];
    #pragma unroll
    for (int mt = 0; mt < 2; ++mt)
        #pragma unroll
        for (int nt = 0; nt < 4; ++nt)
            acc[mt][nt] = (f32x4){0.f, 0.f, 0.f, 0.f};

    for (int i0 = 0; i0 < NPIX; i0 += 32) {
        // ---- stage 1: E-tile (i0..i0+31) x (j0..j0+63)
        f32x4 e0 = (f32x4){0.f, 0.f, 0.f, 0.f};
        f32x4 e1 = (f32x4){0.f, 0.f, 0.f, 0.f};
        {
            const f16* qc = qp + (size_t)i0 * QKLD;
            f16x8 a00 = *(const f16x8*)(qc);
            f16x8 a10 = *(const f16x8*)(qc + (size_t)16 * QKLD);
            f16x8 a01 = *(const f16x8*)(qc + 32);
            f16x8 a11 = *(const f16x8*)(qc + (size_t)16 * QKLD + 32);
            e0 = __builtin_amdgcn_mfma_f32_16x16x32_f16(a00, kf0, e0, 0, 0, 0);
            e1 = __builtin_amdgcn_mfma_f32_16x16x32_f16(a10, kf0, e1, 0, 0, 0);
            e0 = __builtin_amdgcn_mfma_f32_16x16x32_f16(a01, kf1, e0, 0, 0, 0);
            e1 = __builtin_amdgcn_mfma_f32_16x16x32_f16(a11, kf1, e1, 0, 0, 0);
        }
        f16x4 h0 = { (f16)__expf(e0[0]), (f16)__expf(e0[1]),
                     (f16)__expf(e0[2]), (f16)__expf(e0[3]) };
        f16x4 h1 = { (f16)__expf(e1[0]), (f16)__expf(e1[1]),
                     (f16)__expf(e1[2]), (f16)__expf(e1[3]) };
        __syncthreads();   // prior stage-2 reads of es complete
        // lane owns (j = 16w+l16, i = 16mt+quad*4+r): 8B writes, conflict-free
        {
            f16* erow = &es[(16 * w + l16) * 36];
            *(f16x4*)(erow + quad * 4)      = h0;
            *(f16x4*)(erow + 16 + quad * 4) = h1;
        }
        __syncthreads();
        // ---- stage 2: acc[c-tile][j-tile] += u x E
        f16x8 af0 = *(const f16x8*)(up0 + i0 + quad * 8);
        f16x8 af1 = *(const f16x8*)(up1 + i0 + quad * 8);
        #pragma unroll
        for (int nt = 0; nt < 4; ++nt) {
            const f16* eb = &es[(16 * nt + l16) * 36 + quad * 8];
            f16x4 lo = *(const f16x4*)(eb);
            f16x4 hi = *(const f16x4*)(eb + 4);
            f16x8 bf = __builtin_shufflevector(lo, hi, 0, 1, 2, 3, 4, 5, 6, 7);
            acc[0][nt] = __builtin_amdgcn_mfma_f32_16x16x32_f16(af0, bf, acc[0][nt], 0, 0, 0);
            acc[1][nt] = __builtin_amdgcn_mfma_f32_16x16x32_f16(af1, bf, acc[1][nt], 0, 0, 0);
        }
    }

    #pragma unroll
    for (int mt = 0; mt < 2; ++mt) {
        int cb = c0 + 32 * w + 16 * mt + quad * 4;
        #pragma unroll
        for (int nt = 0; nt < 4; ++nt) {
            int j = j0 + 16 * nt + l16;
            f16x4 h = { (f16)acc[mt][nt][0], (f16)acc[mt][nt][1],
                        (f16)acc[mt][nt][2], (f16)acc[mt][nt][3] };
            *(f16x4*)&o1T[((size_t)b * NPIX + j) * CIN + cb] = h;
        }
    }
}

// ---------------------------------------------------------------------------
// Gamma conv via MFMA: out[b,o,j] = sum_c Wg[o,c]*o1[c,j] + gb[o], fp32 out.
// Tile 128(o) x 64(j), BK=32. grid (N/64, C/128, B), block 256.
// ---------------------------------------------------------------------------
__global__ __launch_bounds__(256) void gamma_conv_mfma(
    const f16* __restrict__ o1T, const f16* __restrict__ Wg,
    const float* __restrict__ gbias, float* __restrict__ out)
{
    __shared__ __align__(16) f16 As[128 * 40];
    __shared__ __align__(16) f16 Bs[64 * 40];
    const int t = threadIdx.x, w = t >> 6, lane = t & 63;
    const int quad = lane >> 4, l16 = lane & 15;
    const int wm = w & 1, wn = w >> 1;
    const int j0 = blockIdx.x * 64, o0 = blockIdx.y * 128, b = blockIdx.z;
    const int sub = t >> 2, le = t & 3;
    const f16* srcA = Wg + (size_t)(o0 + sub) * CIN + le * 8;
    const f16* srcB = o1T + ((size_t)b * NPIX + j0 + sub) * CIN + le * 8;
    const int ldsw = sub * 40 + le * 8;

    f32x4 acc[4][2];
    #pragma unroll
    for (int mt = 0; mt < 4; ++mt)
        #pragma unroll
        for (int nt = 0; nt < 2; ++nt)
            acc[mt][nt] = (f32x4){0.f, 0.f, 0.f, 0.f};

    for (int kk = 0; kk < CIN; kk += 32) {
        f16x8 ta0 = *(const f16x8*)(srcA + kk);
        f16x8 ta1 = *(const f16x8*)(srcA + (size_t)64 * CIN + kk);
        f16x8 tb0 = *(const f16x8*)(srcB + kk);
        __syncthreads();
        *(f16x8*)&As[ldsw]           = ta0;
        *(f16x8*)&As[64 * 40 + ldsw] = ta1;
        *(f16x8*)&Bs[ldsw]           = tb0;
        __syncthreads();
        f16x8 af[4], bf[2];
        #pragma unroll
        for (int mt = 0; mt < 4; ++mt)
            af[mt] = *(const f16x8*)&As[(64 * wm + 16 * mt + l16) * 40 + quad * 8];
        #pragma unroll
        for (int nt = 0; nt < 2; ++nt)
            bf[nt] = *(const f16x8*)&Bs[(32 * wn + 16 * nt + l16) * 40 + quad * 8];
        #pragma unroll
        for (int mt = 0; mt < 4; ++mt)
            #pragma unroll
            for (int nt = 0; nt < 2; ++nt)
                acc[mt][nt] = __builtin_amdgcn_mfma_f32_16x16x32_f16(
                    af[mt], bf[nt], acc[mt][nt], 0, 0, 0);
    }

    #pragma unroll
    for (int mt = 0; mt < 4; ++mt)
        #pragma unroll
        for (int r = 0; r < 4; ++r) {
            int o = o0 + 64 * wm + 16 * mt + quad * 4 + r;
            float bv = gbias[o];
            #pragma unroll
            for (int nt = 0; nt < 2; ++nt) {
                int j = j0 + 32 * wn + 16 * nt + l16;
                out[((size_t)b * CIN + o) * NPIX + j] = acc[mt][nt][r] + bv;
            }
        }
}

// ---------------------------------------------------------------------------
extern "C" void kernel_launch(void* const* d_in, const int* in_sizes, int n_in,
                              void* d_out, int out_size, void* d_ws, size_t ws_size,
                              hipStream_t stream) {
    const float* x   = (const float*)d_in[0];
    const float* qw  = (const float*)d_in[1];
    const float* qbv = (const float*)d_in[2];
    const float* kw  = (const float*)d_in[3];
    const float* kbv = (const float*)d_in[4];
    const float* vw  = (const float*)d_in[5];
    const float* vbv = (const float*)d_in[6];
    const float* gw  = (const float*)d_in[7];
    const float* gbv = (const float*)d_in[8];
    float* out = (float*)d_out;

    const size_t BCN  = (size_t)BATCH * CIN * NPIX;   // 4,718,592
    const size_t BN   = (size_t)BATCH * NPIX;         // 18,432
    const size_t BNQK = (size_t)BATCH * NPIX * QKLD;  // 2,359,296

    // ws layout (~33 MB, all f16 except S)
    f16* u    = (f16*)d_ws;
    f16* xT   = u + BCN;
    f16* qkT  = xT + BCN;
    f16* o1T  = qkT + BNQK;
    f16* Wqk  = o1T + BCN;
    f16* Wv   = Wqk + 128 * 256;
    f16* Wg   = Wv + 256 * 256;
    float* S  = (float*)(Wg + 256 * 256);

    hipMemsetAsync(S, 0, BN * sizeof(float), stream);

    cast_w<<<160, 256, 0, stream>>>(qw, kw, vw, gw, Wqk, Wv, Wg);
    cast_xT<<<dim3(NPIX / 64, CIN / 64, BATCH), 256, 0, stream>>>(x, xT);
    qk_conv_mfma<<<dim3(NPIX / 32, BATCH), 256, 0, stream>>>(xT, Wqk, qbv, kbv, qkT);
    energy_S<<<dim3(NPIX / 64, NPIX / 64, BATCH), 256, 0, stream>>>(qkT, S);
    v_conv_mfma<<<dim3(NPIX / 64, CIN / 128, BATCH), 256, 0, stream>>>(xT, Wv, vbv, S, u);
    fused_bmm<<<dim3(NPIX / 64, CIN / 128, BATCH), 256, 0, stream>>>(qkT, u, o1T);
    gamma_conv_mfma<<<dim3(NPIX / 64, CIN / 128, BATCH), 256, 0, stream>>>(o1T, Wg, gbv, out);
}

// Round 6
// 225.403 us; speedup vs baseline: 1.4424x; 1.4424x over previous
//
#include <hip/hip_runtime.h>

// B=8, C=256, H=W=48 -> N=2304, k=4 -> CK=64
#define BATCH 8
#define CIN   256
#define NPIX  2304
#define CKD   64
#define QKLD  128          // qkT row stride (q cols 0-63, k cols 64-127)
#define KSPL  3
#define KLEN  (NPIX / KSPL)   // 768 per K-split

typedef _Float16 f16;
typedef __attribute__((ext_vector_type(4))) _Float16 f16x4;
typedef __attribute__((ext_vector_type(8))) _Float16 f16x8;
typedef __attribute__((ext_vector_type(4))) float    f32x4;

// ---------------------------------------------------------------------------
// Cast all conv weights fp32 -> f16. Wqk = [qw (64x256); kw (64x256)].
// ---------------------------------------------------------------------------
__global__ __launch_bounds__(256) void cast_w(
    const float* __restrict__ qw, const float* __restrict__ kw,
    const float* __restrict__ vw, const float* __restrict__ gw,
    f16* __restrict__ Wqk, f16* __restrict__ Wv, f16* __restrict__ Wg)
{
    int idx = (blockIdx.x * 256 + threadIdx.x) * 4;
    const float* src;
    f16* dst;
    if (idx < 16384)      { src = qw + idx;           dst = Wqk + idx; }
    else if (idx < 32768) { src = kw + (idx - 16384); dst = Wqk + idx; }
    else if (idx < 98304) { src = vw + (idx - 32768); dst = Wv + (idx - 32768); }
    else                  { src = gw + (idx - 98304); dst = Wg + (idx - 98304); }
    float4 v = *(const float4*)src;
    f16x4 h = { (f16)v.x, (f16)v.y, (f16)v.z, (f16)v.w };
    *(f16x4*)dst = h;
}

// ---------------------------------------------------------------------------
// x[b][c][n] fp32 -> xT[b][n][c] f16 (LDS transpose). Tile 64c x 64n.
// ---------------------------------------------------------------------------
__global__ __launch_bounds__(256) void cast_xT(
    const float* __restrict__ x, f16* __restrict__ xT)
{
    __shared__ float s[64][65];
    const int t = threadIdx.x;
    const int n0 = blockIdx.x * 64, c0 = blockIdx.y * 64, b = blockIdx.z;
    const float* xb = x + ((size_t)b * CIN + c0) * NPIX + n0;

    const int cl = t >> 4, ng = (t & 15) * 4;
    #pragma unroll
    for (int p = 0; p < 4; ++p) {
        float4 v = *(const float4*)(xb + (size_t)(cl + 16 * p) * NPIX + ng);
        s[cl + 16 * p][ng + 0] = v.x;
        s[cl + 16 * p][ng + 1] = v.y;
        s[cl + 16 * p][ng + 2] = v.z;
        s[cl + 16 * p][ng + 3] = v.w;
    }
    __syncthreads();
    const int nl = t >> 2, cs = (t & 3) * 16;
    f16 h[16];
    #pragma unroll
    for (int j = 0; j < 16; ++j) h[j] = (f16)s[cs + j][nl];
    f16* gp = &xT[((size_t)b * NPIX + n0 + nl) * CIN + c0 + cs];
    *(f16x8*)gp       = *(f16x8*)&h[0];
    *(f16x8*)(gp + 8) = *(f16x8*)&h[8];
}

// ---------------------------------------------------------------------------
// q & k conv via MFMA: qkT[b][n][o], o<64 = q, o>=64 = k.
// grid (N/32, B), block 256.
// ---------------------------------------------------------------------------
__global__ __launch_bounds__(256) void qk_conv_mfma(
    const f16* __restrict__ xT, const f16* __restrict__ Wqk,
    const float* __restrict__ qbias, const float* __restrict__ kbias,
    f16* __restrict__ qkT)
{
    const int t = threadIdx.x, w = t >> 6, lane = t & 63;
    const int quad = lane >> 4, l16 = lane & 15;
    const int wm = w & 1, wn = w >> 1;
    const int n0 = blockIdx.x * 32, b = blockIdx.y;

    const f16* bp = xT + ((size_t)b * NPIX + n0 + 16 * wn + l16) * CIN;
    const f16* ap = Wqk + (size_t)(64 * wm + l16) * CIN;

    f32x4 acc[4];
    #pragma unroll
    for (int mt = 0; mt < 4; ++mt) acc[mt] = (f32x4){0.f, 0.f, 0.f, 0.f};

    #pragma unroll
    for (int kk = 0; kk < CIN; kk += 32) {
        f16x8 bf = *(const f16x8*)(bp + kk + quad * 8);
        #pragma unroll
        for (int mt = 0; mt < 4; ++mt) {
            f16x8 af = *(const f16x8*)(ap + (size_t)mt * 16 * CIN + kk + quad * 8);
            acc[mt] = __builtin_amdgcn_mfma_f32_16x16x32_f16(af, bf, acc[mt], 0, 0, 0);
        }
    }
    const int n = n0 + 16 * wn + l16;
    const float* bias = wm ? kbias - 64 : qbias;   // o-indexed
    #pragma unroll
    for (int mt = 0; mt < 4; ++mt) {
        int ob = 64 * wm + 16 * mt + quad * 4;
        f16x4 h;
        #pragma unroll
        for (int r = 0; r < 4; ++r)
            h[r] = (f16)(acc[mt][r] + bias[ob + r]);
        *(f16x4*)&qkT[((size_t)b * NPIX + n) * QKLD + ob] = h;
    }
}

// ---------------------------------------------------------------------------
// Energy via MFMA: e[i,j] = exp(q_i . k_j). Writes Et[b,j,i] f16 (coalesced
// via LDS transpose) and row sums S[b,i] (atomicAdd from the f16 tile).
// grid (N/64 j, N/64 i, B), block 256.
// ---------------------------------------------------------------------------
__global__ __launch_bounds__(256) void energy_mfma(
    const f16* __restrict__ qkT, float* __restrict__ S, f16* __restrict__ Et)
{
    __shared__ f16   es[64][72];
    __shared__ float red2[4][64];
    const int t    = threadIdx.x;
    const int w    = t >> 6, lane = t & 63;
    const int quad = lane >> 4, l16 = lane & 15;
    const int j0 = blockIdx.x * 64, i0 = blockIdx.y * 64, b = blockIdx.z;
    const f16* base = qkT + (size_t)b * NPIX * QKLD;

    f32x4 acc[4];
    #pragma unroll
    for (int mt = 0; mt < 4; ++mt) acc[mt] = (f32x4){0.f, 0.f, 0.f, 0.f};

    #pragma unroll
    for (int ks = 0; ks < 2; ++ks) {
        f16x8 bf = *(const f16x8*)&base[(size_t)(j0 + 16 * w + l16) * QKLD + 64 + ks * 32 + quad * 8];
        #pragma unroll
        for (int mt = 0; mt < 4; ++mt) {
            f16x8 af = *(const f16x8*)&base[(size_t)(i0 + 16 * mt + l16) * QKLD + ks * 32 + quad * 8];
            acc[mt] = __builtin_amdgcn_mfma_f32_16x16x32_f16(af, bf, acc[mt], 0, 0, 0);
        }
    }

    #pragma unroll
    for (int mt = 0; mt < 4; ++mt) {
        f16x4 h = { (f16)__expf(acc[mt][0]), (f16)__expf(acc[mt][1]),
                    (f16)__expf(acc[mt][2]), (f16)__expf(acc[mt][3]) };
        *(f16x4*)&es[16 * w + l16][16 * mt + quad * 4] = h;
    }
    __syncthreads();

    {
        int j = t >> 2, ch = (t & 3) * 16;
        f16x8 v0 = *(const f16x8*)&es[j][ch];
        f16x8 v1 = *(const f16x8*)&es[j][ch + 8];
        f16* gp = &Et[((size_t)b * NPIX + j0 + j) * NPIX + i0 + ch];
        *(f16x8*)gp       = v0;
        *(f16x8*)(gp + 8) = v1;
    }
    {
        int i = t & 63, jq = t >> 6;
        float s = 0.f;
        #pragma unroll
        for (int jj = 0; jj < 16; ++jj)
            s += (float)es[jq * 16 + jj][i];
        red2[jq][i] = s;
    }
    __syncthreads();
    if (t < 64) {
        float s = red2[0][t] + red2[1][t] + red2[2][t] + red2[3][t];
        atomicAdd(&S[(size_t)b * NPIX + i0 + t], s);
    }
}

// ---------------------------------------------------------------------------
// v conv via MFMA, fused bias + 1/S scale: u[b,c,i] f16.
// Tile 128(c) x 64(i), BK=32, LDS-staged. grid (N/64, C/128, B), block 256.
// ---------------------------------------------------------------------------
__global__ __launch_bounds__(256) void v_conv_mfma(
    const f16* __restrict__ xT, const f16* __restrict__ Wv,
    const float* __restrict__ vbias, const float* __restrict__ S,
    f16* __restrict__ u)
{
    __shared__ __align__(16) f16 As[128 * 40];
    __shared__ __align__(16) f16 Bs[64 * 40];
    const int t = threadIdx.x, w = t >> 6, lane = t & 63;
    const int quad = lane >> 4, l16 = lane & 15;
    const int wm = w & 1, wn = w >> 1;
    const int i0 = blockIdx.x * 64, c0 = blockIdx.y * 128, b = blockIdx.z;
    const int sub = t >> 2, le = t & 3;
    const f16* srcA = Wv + (size_t)(c0 + sub) * CIN + le * 8;
    const f16* srcB = xT + ((size_t)b * NPIX + i0 + sub) * CIN + le * 8;
    const int ldsw = sub * 40 + le * 8;

    f32x4 acc[4][2];
    #pragma unroll
    for (int mt = 0; mt < 4; ++mt)
        #pragma unroll
        for (int nt = 0; nt < 2; ++nt)
            acc[mt][nt] = (f32x4){0.f, 0.f, 0.f, 0.f};

    for (int kk = 0; kk < CIN; kk += 32) {
        f16x8 ta0 = *(const f16x8*)(srcA + kk);
        f16x8 ta1 = *(const f16x8*)(srcA + (size_t)64 * CIN + kk);
        f16x8 tb0 = *(const f16x8*)(srcB + kk);
        __syncthreads();
        *(f16x8*)&As[ldsw]           = ta0;
        *(f16x8*)&As[64 * 40 + ldsw] = ta1;
        *(f16x8*)&Bs[ldsw]           = tb0;
        __syncthreads();
        f16x8 af[4], bf[2];
        #pragma unroll
        for (int mt = 0; mt < 4; ++mt)
            af[mt] = *(const f16x8*)&As[(64 * wm + 16 * mt + l16) * 40 + quad * 8];
        #pragma unroll
        for (int nt = 0; nt < 2; ++nt)
            bf[nt] = *(const f16x8*)&Bs[(32 * wn + 16 * nt + l16) * 40 + quad * 8];
        #pragma unroll
        for (int mt = 0; mt < 4; ++mt)
            #pragma unroll
            for (int nt = 0; nt < 2; ++nt)
                acc[mt][nt] = __builtin_amdgcn_mfma_f32_16x16x32_f16(
                    af[mt], bf[nt], acc[mt][nt], 0, 0, 0);
    }

    #pragma unroll
    for (int nt = 0; nt < 2; ++nt) {
        int i = i0 + 32 * wn + 16 * nt + l16;
        float is = 1.0f / S[(size_t)b * NPIX + i];
        #pragma unroll
        for (int mt = 0; mt < 4; ++mt)
            #pragma unroll
            for (int r = 0; r < 4; ++r) {
                int c = c0 + 64 * wm + 16 * mt + quad * 4 + r;
                u[((size_t)b * CIN + c) * NPIX + i] =
                    (f16)((acc[mt][nt][r] + vbias[c]) * is);
            }
    }
}

// ---------------------------------------------------------------------------
// MFMA bmm: o1T[b,j,c] = sum_i u[b,c,i]*Et[b,j,i], K-split 3 -> p0/p1/p2 f16.
// Tile 256(c) x 128(j), BK=32. Block 512 thr = 8 waves (4c x 2j of 64x64).
// XOR-swizzled LDS (chunk' = chunk ^ ((row>>1)&3)): staging stores and
// ds_read_b128 frag reads are both 2-way max = conflict-free (m136).
// grid (N/128, KSPL, B).
// ---------------------------------------------------------------------------
__global__ __launch_bounds__(512, 2) void bmm_mfma(
    const f16* __restrict__ u, const f16* __restrict__ Et,
    f16* __restrict__ p0, f16* __restrict__ p1, f16* __restrict__ p2)
{
    __shared__ __align__(16) f16 As[256 * 32];   // rows c, swizzled chunks
    __shared__ __align__(16) f16 Bs[128 * 32];   // rows j, swizzled chunks
    const int t = threadIdx.x, w = t >> 6, lane = t & 63;
    const int quad = lane >> 4, l16 = lane & 15;
    const int wc = w & 3, wj = w >> 2;           // wave tile: c 64*wc, j 64*wj
    const int j0 = blockIdx.x * 128;
    const int ks = blockIdx.y, b = blockIdx.z;
    const int kb = ks * KLEN;
    const f16* ub = u  + (size_t)b * CIN * NPIX;
    const f16* eb = Et + (size_t)b * NPIX * NPIX;
    f16* outp = (ks == 0) ? p0 : (ks == 1 ? p1 : p2);

    // staging: thread t -> row t>>2, swizzled chunk t&3, data chunk chd
    const int rA  = t >> 2;
    const int chp = t & 3;
    const int chd = chp ^ ((t >> 3) & 3);
    const f16* srcA0 = ub + (size_t)rA * NPIX + kb + chd * 8;
    const f16* srcA1 = srcA0 + (size_t)128 * NPIX;
    const f16* srcB  = eb + (size_t)(j0 + rA) * NPIX + kb + chd * 8;
    const int ldsA0 = rA * 32 + chp * 8;
    const int ldsA1 = (rA + 128) * 32 + chp * 8;
    const int ldsB  = rA * 32 + chp * 8;
    // frag-read swizzle (wave-constant per lane)
    const int swz = (quad ^ ((l16 >> 1) & 3)) * 8;

    f32x4 acc[4][4];
    #pragma unroll
    for (int mt = 0; mt < 4; ++mt)
        #pragma unroll
        for (int nt = 0; nt < 4; ++nt)
            acc[mt][nt] = (f32x4){0.f, 0.f, 0.f, 0.f};

    for (int kk = 0; kk < KLEN; kk += 32) {
        f16x8 ta0 = *(const f16x8*)(srcA0 + kk);
        f16x8 ta1 = *(const f16x8*)(srcA1 + kk);
        f16x8 tb0 = *(const f16x8*)(srcB + kk);
        __syncthreads();
        *(f16x8*)&As[ldsA0] = ta0;
        *(f16x8*)&As[ldsA1] = ta1;
        *(f16x8*)&Bs[ldsB]  = tb0;
        __syncthreads();
        f16x8 af[4], bf[4];
        #pragma unroll
        for (int mt = 0; mt < 4; ++mt)
            af[mt] = *(const f16x8*)&As[(64 * wc + 16 * mt + l16) * 32 + swz];
        #pragma unroll
        for (int nt = 0; nt < 4; ++nt)
            bf[nt] = *(const f16x8*)&Bs[(64 * wj + 16 * nt + l16) * 32 + swz];
        #pragma unroll
        for (int mt = 0; mt < 4; ++mt)
            #pragma unroll
            for (int nt = 0; nt < 4; ++nt)
                acc[mt][nt] = __builtin_amdgcn_mfma_f32_16x16x32_f16(
                    af[mt], bf[nt], acc[mt][nt], 0, 0, 0);
    }

    #pragma unroll
    for (int mt = 0; mt < 4; ++mt) {
        int cb = 64 * wc + 16 * mt + quad * 4;
        #pragma unroll
        for (int nt = 0; nt < 4; ++nt) {
            int j = j0 + 64 * wj + 16 * nt + l16;
            f16x4 h = { (f16)acc[mt][nt][0], (f16)acc[mt][nt][1],
                        (f16)acc[mt][nt][2], (f16)acc[mt][nt][3] };
            *(f16x4*)&outp[((size_t)b * NPIX + j) * CIN + cb] = h;
        }
    }
}

// ---------------------------------------------------------------------------
// Gamma conv via MFMA: out[b,o,j] = sum_c Wg[o,c]*(p0+p1+p2)[j,c] + gb[o].
// Tile 128(o) x 64(j), BK=32, fp32 out. grid (N/64, C/128, B), block 256.
// ---------------------------------------------------------------------------
__global__ __launch_bounds__(256) void gamma_conv_mfma(
    const f16* __restrict__ p0, const f16* __restrict__ p1,
    const f16* __restrict__ p2, const f16* __restrict__ Wg,
    const float* __restrict__ gbias, float* __restrict__ out)
{
    __shared__ __align__(16) f16 As[128 * 40];
    __shared__ __align__(16) f16 Bs[64 * 40];
    const int t = threadIdx.x, w = t >> 6, lane = t & 63;
    const int quad = lane >> 4, l16 = lane & 15;
    const int wm = w & 1, wn = w >> 1;
    const int j0 = blockIdx.x * 64, o0 = blockIdx.y * 128, b = blockIdx.z;
    const int sub = t >> 2, le = t & 3;
    const f16* srcA  = Wg + (size_t)(o0 + sub) * CIN + le * 8;
    const size_t boff = ((size_t)b * NPIX + j0 + sub) * CIN + le * 8;
    const int ldsw = sub * 40 + le * 8;

    f32x4 acc[4][2];
    #pragma unroll
    for (int mt = 0; mt < 4; ++mt)
        #pragma unroll
        for (int nt = 0; nt < 2; ++nt)
            acc[mt][nt] = (f32x4){0.f, 0.f, 0.f, 0.f};

    for (int kk = 0; kk < CIN; kk += 32) {
        f16x8 ta0 = *(const f16x8*)(srcA + kk);
        f16x8 ta1 = *(const f16x8*)(srcA + (size_t)64 * CIN + kk);
        f16x8 tb0 = *(const f16x8*)(p0 + boff + kk);
        f16x8 tb1 = *(const f16x8*)(p1 + boff + kk);
        f16x8 tb2 = *(const f16x8*)(p2 + boff + kk);
        f16x8 tbs = tb0 + tb1 + tb2;
        __syncthreads();
        *(f16x8*)&As[ldsw]           = ta0;
        *(f16x8*)&As[64 * 40 + ldsw] = ta1;
        *(f16x8*)&Bs[ldsw]           = tbs;
        __syncthreads();
        f16x8 af[4], bf[2];
        #pragma unroll
        for (int mt = 0; mt < 4; ++mt)
            af[mt] = *(const f16x8*)&As[(64 * wm + 16 * mt + l16) * 40 + quad * 8];
        #pragma unroll
        for (int nt = 0; nt < 2; ++nt)
            bf[nt] = *(const f16x8*)&Bs[(32 * wn + 16 * nt + l16) * 40 + quad * 8];
        #pragma unroll
        for (int mt = 0; mt < 4; ++mt)
            #pragma unroll
            for (int nt = 0; nt < 2; ++nt)
                acc[mt][nt] = __builtin_amdgcn_mfma_f32_16x16x32_f16(
                    af[mt], bf[nt], acc[mt][nt], 0, 0, 0);
    }

    #pragma unroll
    for (int mt = 0; mt < 4; ++mt)
        #pragma unroll
        for (int r = 0; r < 4; ++r) {
            int o = o0 + 64 * wm + 16 * mt + quad * 4 + r;
            float bv = gbias[o];
            #pragma unroll
            for (int nt = 0; nt < 2; ++nt) {
                int j = j0 + 32 * wn + 16 * nt + l16;
                out[((size_t)b * CIN + o) * NPIX + j] = acc[mt][nt][r] + bv;
            }
        }
}

// ---------------------------------------------------------------------------
extern "C" void kernel_launch(void* const* d_in, const int* in_sizes, int n_in,
                              void* d_out, int out_size, void* d_ws, size_t ws_size,
                              hipStream_t stream) {
    const float* x   = (const float*)d_in[0];
    const float* qw  = (const float*)d_in[1];
    const float* qbv = (const float*)d_in[2];
    const float* kw  = (const float*)d_in[3];
    const float* kbv = (const float*)d_in[4];
    const float* vw  = (const float*)d_in[5];
    const float* vbv = (const float*)d_in[6];
    const float* gw  = (const float*)d_in[7];
    const float* gbv = (const float*)d_in[8];
    float* out = (float*)d_out;

    const size_t BCN  = (size_t)BATCH * CIN * NPIX;   // 4,718,592
    const size_t BN   = (size_t)BATCH * NPIX;         // 18,432
    const size_t BNN  = (size_t)BATCH * NPIX * NPIX;  // 42,467,328
    const size_t BNQK = (size_t)BATCH * NPIX * QKLD;  // 2,359,296

    // ws layout (~128 MB). xT is dead after v_conv; bmm partial p0 reuses it.
    f16* Et   = (f16*)d_ws;          // 84.93 MB
    f16* u    = Et + BNN;            //  9.44 MB
    f16* xT   = u + BCN;             //  9.44 MB (reused as p0)
    f16* qkT  = xT + BCN;            //  4.72 MB
    f16* p1   = qkT + BNQK;          //  9.44 MB
    f16* p2   = p1 + BCN;            //  9.44 MB
    f16* Wqk  = p2 + BCN;
    f16* Wv   = Wqk + 128 * 256;
    f16* Wg   = Wv + 256 * 256;
    float* S  = (float*)(Wg + 256 * 256);
    f16* p0   = xT;

    hipMemsetAsync(S, 0, BN * sizeof(float), stream);

    cast_w<<<160, 256, 0, stream>>>(qw, kw, vw, gw, Wqk, Wv, Wg);
    cast_xT<<<dim3(NPIX / 64, CIN / 64, BATCH), 256, 0, stream>>>(x, xT);
    qk_conv_mfma<<<dim3(NPIX / 32, BATCH), 256, 0, stream>>>(xT, Wqk, qbv, kbv, qkT);
    energy_mfma<<<dim3(NPIX / 64, NPIX / 64, BATCH), 256, 0, stream>>>(qkT, S, Et);
    v_conv_mfma<<<dim3(NPIX / 64, CIN / 128, BATCH), 256, 0, stream>>>(xT, Wv, vbv, S, u);
    bmm_mfma<<<dim3(NPIX / 128, KSPL, BATCH), 512, 0, stream>>>(u, Et, p0, p1, p2);
    gamma_conv_mfma<<<dim3(NPIX / 64, CIN / 128, BATCH), 256, 0, stream>>>(p0, p1, p2, Wg, gbv, out);
}